// Round 9
// baseline (1443.701 us; speedup 1.0000x reference)
//
#include <hip/hip_runtime.h>
#include <math.h>

// GatedPrototypeDistillationLoss, MI355X gfx950 — round 9.
//  * kmain_v7: 512-thread blocks (8 waves) on the SAME BM=64/BK=32, 80KB-LDS
//    schedule -> 16 waves/CU (was 8). Wave tile 32r x 64p (acc 32 VGPR);
//    softmax state unchanged (16 rows/lane). Staging: exactly 5
//    global_load_lds per wave per step (4 B + 1 A) -> vmcnt(5).
//    Round-8 event model: MFMA busy 38%, LDS 47%, neither saturated ->
//    overlap-limited at 8 waves/CU; doubling waves targets max(LDS,MFMA).
//  * kprep_p/e2, krescore4, kreduce2, ws layout: unchanged from round 8.

#define NB 32768
#define ND 512
#define NK 2048
#define TEMPR 0.07f
#define INV_T 14.285714285714286f
#define DX 1.4285714e-4f  // near-tie margin in x-domain (=1e-5 sim / T)

typedef unsigned short u16;
typedef unsigned long long u64;
using bf16x8 = __attribute__((ext_vector_type(8))) short;
using u16x8 = __attribute__((ext_vector_type(8))) unsigned short;
using f32x16 = __attribute__((ext_vector_type(16))) float;

__device__ inline u16 bf_hi(float x) {  // fp32 -> bf16 bits, RNE
  unsigned u = __float_as_uint(x);
  u = u + 0x7FFFu + ((u >> 16) & 1u);
  return (u16)(u >> 16);
}
__device__ inline float bf_tof(u16 h) {
  return __uint_as_float(((unsigned)h) << 16);
}
__device__ inline void gload_lds16(const void* g, void* l) {
  __builtin_amdgcn_global_load_lds((const __attribute__((address_space(1))) void*)g,
                                   (__attribute__((address_space(3))) void*)l, 16, 0, 0);
}
#define MF(a, b, c) __builtin_amdgcn_mfma_f32_32x32x16_bf16((a), (b), (c), 0, 0, 0)

#define WAIT_LGKM0 { asm volatile("s_waitcnt lgkmcnt(0)" ::: "memory"); \
                     __builtin_amdgcn_sched_barrier(0); }
#define WAIT_VM5   { asm volatile("s_waitcnt vmcnt(5)" ::: "memory"); \
                     __builtin_amdgcn_sched_barrier(0); }
#define SBAR       { __builtin_amdgcn_s_barrier(); \
                     __builtin_amdgcn_sched_barrier(0); }

// ---- kernel 1: P -> normalized bf16 hi/lo (transposed tiles) + inv_p -------
// Phi/Plo u16 layout: [kt(8)][gd(64)][proto(256)][8]
__global__ __launch_bounds__(256) void kprep_p(const float* __restrict__ P,
                                               u16* __restrict__ Phi,
                                               u16* __restrict__ Plo,
                                               float* __restrict__ invp,
                                               int* __restrict__ cnt) {
  if (blockIdx.x == 0 && threadIdx.x == 0) *cnt = 0;
  const int lane = threadIdx.x & 63, w = threadIdx.x >> 6;
  const int p = blockIdx.x * 4 + w;  // grid 512 -> 2048 rows
  const float4* pr = (const float4*)(P + (size_t)p * ND);
  float4 a = pr[2 * lane], b = pr[2 * lane + 1];  // granule `lane`: d=8*lane..+7
  float ss = a.x * a.x + a.y * a.y + a.z * a.z + a.w * a.w
           + b.x * b.x + b.y * b.y + b.z * b.z + b.w * b.w;
#pragma unroll
  for (int off = 32; off > 0; off >>= 1) ss += __shfl_xor(ss, off);
  const float inv = 1.0f / fmaxf(sqrtf(ss), 1e-12f);
  if (lane == 0) invp[p] = inv;
  u16x8 h8, l8;
#define PCNV(j, f) { float n_ = (f) * inv; u16 hb_ = bf_hi(n_); \
  h8[j] = hb_; l8[j] = bf_hi(n_ - bf_tof(hb_)); }
  PCNV(0, a.x) PCNV(1, a.y) PCNV(2, a.z) PCNV(3, a.w)
  PCNV(4, b.x) PCNV(5, b.y) PCNV(6, b.z) PCNV(7, b.w)
#undef PCNV
  const int kt = p >> 8, pl = p & 255;
  const size_t idx = ((size_t)((kt * 16 + (lane >> 2)) * 4 + (lane & 3)) * 256 + pl) * 8;
  *(u16x8*)(Phi + idx) = h8;
  *(u16x8*)(Plo + idx) = l8;
}

// ---------------- kernel 2: E -> normalized bf16 hi/lo (row-major) ----------
__global__ __launch_bounds__(256) void kprep_e2(const float* __restrict__ E,
                                                u16* __restrict__ Ehi,
                                                u16* __restrict__ Elo) {
  const int lane = threadIdx.x & 63, w = threadIdx.x >> 6;
  const int row = blockIdx.x * 4 + w;  // grid 8192 -> 32768 rows
  const float4* er = (const float4*)(E + (size_t)row * ND);
  float4 a = er[lane], b = er[lane + 64];
  float ss = a.x * a.x + a.y * a.y + a.z * a.z + a.w * a.w
           + b.x * b.x + b.y * b.y + b.z * b.z + b.w * b.w;
#pragma unroll
  for (int off = 32; off > 0; off >>= 1) ss += __shfl_xor(ss, off);
  const float inv = 1.0f / fmaxf(sqrtf(ss), 1e-12f);
  ushort4 h4, l4;
#define PCNV(dst_h, dst_l, f) { float n_ = (f) * inv; u16 hb_ = bf_hi(n_); \
  dst_h = hb_; dst_l = bf_hi(n_ - bf_tof(hb_)); }
  PCNV(h4.x, l4.x, a.x) PCNV(h4.y, l4.y, a.y) PCNV(h4.z, l4.z, a.z) PCNV(h4.w, l4.w, a.w)
  *(ushort4*)(Ehi + (size_t)row * ND + lane * 4) = h4;
  *(ushort4*)(Elo + (size_t)row * ND + lane * 4) = l4;
  PCNV(h4.x, l4.x, b.x) PCNV(h4.y, l4.y, b.y) PCNV(h4.z, l4.z, b.z) PCNV(h4.w, l4.w, b.w)
  *(ushort4*)(Ehi + (size_t)row * ND + (lane + 64) * 4) = h4;
  *(ushort4*)(Elo + (size_t)row * ND + (lane + 64) * 4) = l4;
#undef PCNV
}

// online update with exact top-2 tracking (x-domain logit, fixed offset)
#define UPD2(r, vv, pp) { \
  float x_ = fmaf((vv), INV_T, -INV_T); \
  float e_ = __expf(x_); \
  sS[r] += e_; uS[r] = fmaf(x_, e_, uS[r]); \
  bool u1_ = x_ > m1[r]; \
  float lo_ = u1_ ? m1[r] : x_; \
  m2[r] = fmaxf(m2[r], lo_); \
  m1[r] = u1_ ? x_ : m1[r]; \
  ix[r] = u1_ ? (pp) : ix[r]; }

// ====== kernel 3: 8-wave MFMA GEMM, 16 waves/CU, counted-vmcnt pipeline =====
__global__ __launch_bounds__(512, 4) void kmain_v7(
    const float* __restrict__ BS,
    const u16* __restrict__ PhiG, const u16* __restrict__ PloG,
    const u16* __restrict__ EhiG, const u16* __restrict__ EloG,
    const float* __restrict__ CONF,
    float* __restrict__ tau_ws, float* __restrict__ gd, float* __restrict__ gate_out,
    int* __restrict__ cnt, int* __restrict__ flags, u64* __restrict__ pk) {
  // LDS u16 layouts: A [g(4)][row(64)][8] ; B [g(4)][proto(256)][8]
  __shared__ u16 Ahi[2][2048], Alo[2][2048];   // 16 KB
  __shared__ u16 Bhi[2][8192], Blo[2][8192];   // 64 KB

  const int t = threadIdx.x;
  const int lane = t & 63;
  const int w = t >> 6;          // 8 waves
  const int wr = w & 1;          // row half (rows wr*32..+31)
  const int wc = w >> 1;         // proto quarter (protos wc*64..+63)
  const int c = lane & 31, h = lane >> 5;
  const int swz = (blockIdx.x & 7) * 64 + (blockIdx.x >> 3);  // XCD swizzle (512=8*64)
  const int row0 = swz * 64;

  // A staging: waves 0-3 stage Ahi granule w, waves 4-7 stage Alo granule w-4.
  const int ag = w & 3;
  const u16* Asrc = ((w < 4) ? EhiG : EloG) + (size_t)(row0 + lane) * ND + ag * 8;
  const int aslot = (ag * 64 + lane) * 8;

  // B staging: each wave 2 hi + 2 lo instrs; slot index doubles as src offset.
  int boff[2];
#pragma unroll
  for (int i = 0; i < 2; ++i) boff[i] = ((w * 2 + i) * 64 + lane) * 8;

  // fragment-read offsets (u16 units), lane-contiguous 16B -> conflict-free
  const int ao0 = ((0 + h) * 64 + wr * 32 + c) * 8;   // ks=0
  const int ao1 = ((2 + h) * 64 + wr * 32 + c) * 8;   // ks=1
  const int bo0 = ((0 + h) * 256 + wc * 64 + c) * 8;
  const int bo1 = ((2 + h) * 256 + wc * 64 + c) * 8;

  f32x16 acc0, acc1;
#pragma unroll
  for (int i = 0; i < 16; ++i) { acc0[i] = 0.f; acc1[i] = 0.f; }
  float sS[16], uS[16], m1[16], m2[16];
  int ix[16];
#pragma unroll
  for (int r = 0; r < 16; ++r) {
    sS[r] = 0.f; uS[r] = 0.f; m1[r] = -3.0e38f; m2[r] = -3.0e38f; ix[r] = 0;
  }

#define SB7(tile_u16, nx) { \
  _Pragma("unroll") \
  for (int i = 0; i < 2; ++i) { \
    gload_lds16(PhiG + (tile_u16) + boff[i], &Bhi[nx][boff[i]]); \
    gload_lds16(PloG + (tile_u16) + boff[i], &Blo[nx][boff[i]]); \
  } }
#define SA7(col, nx) { \
  if (w < 4) { gload_lds16(Asrc + (col), &Ahi[nx][aslot]); } \
  else       { gload_lds16(Asrc + (col), &Alo[nx][aslot]); } }

  // prologue: stage step 0 -> buf0, step 1 -> buf1; wait step0 only (5 of 10)
  SB7(0, 0);
  SA7(0, 0);
  SB7(8192, 1);
  SA7(32, 1);
  WAIT_VM5;
  SBAR;

#pragma unroll 2
  for (int step = 0; step < 128; ++step) {
    const int cur = step & 1;
    // ---- phase R: all 12 fragment reads from buf[cur] ----
    const bf16x8 eh0 = *(const bf16x8*)&Ahi[cur][ao0];
    const bf16x8 el0 = *(const bf16x8*)&Alo[cur][ao0];
    const bf16x8 eh1 = *(const bf16x8*)&Ahi[cur][ao1];
    const bf16x8 el1 = *(const bf16x8*)&Alo[cur][ao1];
    const bf16x8 bh00 = *(const bf16x8*)&Bhi[cur][bo0];
    const bf16x8 bh01 = *(const bf16x8*)&Bhi[cur][bo0 + 256];
    const bf16x8 bl00 = *(const bf16x8*)&Blo[cur][bo0];
    const bf16x8 bl01 = *(const bf16x8*)&Blo[cur][bo0 + 256];
    const bf16x8 bh10 = *(const bf16x8*)&Bhi[cur][bo1];
    const bf16x8 bh11 = *(const bf16x8*)&Bhi[cur][bo1 + 256];
    const bf16x8 bl10 = *(const bf16x8*)&Blo[cur][bo1];
    const bf16x8 bl11 = *(const bf16x8*)&Blo[cur][bo1 + 256];

    // ---- MFMA ks=0 ----
    acc0 = MF(eh0, bh00, acc0); acc1 = MF(eh0, bh01, acc1);
    acc0 = MF(eh0, bl00, acc0); acc1 = MF(eh0, bl01, acc1);
    acc0 = MF(el0, bh00, acc0); acc1 = MF(el0, bh01, acc1);

    // ---- barrier 1: all waves done READING buf[cur]; no vmcnt drain ----
    WAIT_LGKM0;
    SBAR;

    // ---- phase S: stage step+2 into buf[cur] (5 loads/wave) ----
    const int ns = (step < 126) ? step + 2 : 127;  // tail dup, never read
    SB7(ns * 8192, cur);
    SA7((ns & 15) * 32, cur);

    // ---- MFMA ks=1 ----
    acc0 = MF(eh1, bh10, acc0); acc1 = MF(eh1, bh11, acc1);
    acc0 = MF(eh1, bl10, acc0); acc1 = MF(eh1, bl11, acc1);
    acc0 = MF(el1, bh10, acc0); acc1 = MF(el1, bh11, acc1);

    if ((step & 15) == 15) {  // kt-tile digest (overlaps in-flight stages)
      const int pidb = (step >> 4) * 256 + wc * 64 + c;
#pragma unroll
      for (int r = 0; r < 16; ++r) {
        UPD2(r, acc0[r], pidb)
        UPD2(r, acc1[r], pidb + 32)
        acc0[r] = 0.f; acc1[r] = 0.f;
      }
    }

    // ---- barrier 2: retire ONLY step t+1's 5 loads (counted vmcnt) ----
    WAIT_VM5;
    SBAR;
  }

  __syncthreads();  // full drain (tail dup-stages still write Ahi/Bhi)

  // ---- butterfly merge across the 32 proto-partition lanes ----
#pragma unroll
  for (int off = 1; off < 32; off <<= 1) {
#pragma unroll
    for (int r = 0; r < 16; ++r) {
      float m1o = __shfl_xor(m1[r], off);
      float m2o = __shfl_xor(m2[r], off);
      float so = __shfl_xor(sS[r], off);
      float uo = __shfl_xor(uS[r], off);
      int io = __shfl_xor(ix[r], off);
      sS[r] += so; uS[r] += uo;
      bool up = (m1o > m1[r]) || (m1o == m1[r] && io < ix[r]);
      float losr = (m1o > m1[r]) ? m1[r] : m1o;  // min(m1, m1o)
      m2[r] = fmaxf(fmaxf(m2[r], m2o), losr);
      m1[r] = fmaxf(m1[r], m1o);
      ix[r] = up ? io : ix[r];
    }
  }

  // ---- cross-wave (wc=0..3) merge via LDS (alias onto Ahi, compute done) ----
  float* mg = (float*)&Ahi[0][0];  // [wr(2)][wc(4)][32 rows][6] = 1536 floats (6KB <= 8KB)
  if (c == 0) {
#pragma unroll
    for (int r = 0; r < 16; ++r) {
      int rowl = (r & 3) + 8 * (r >> 2) + 4 * h;
      int base = ((wr * 4 + wc) * 32 + rowl) * 6;
      mg[base + 0] = m1[r];
      mg[base + 1] = sS[r];
      mg[base + 2] = uS[r];
      mg[base + 3] = __int_as_float(ix[r]);
      mg[base + 4] = m2[r];
    }
  }
  __syncthreads();

  if (w < 2 && lane < 32) {  // wave w handles row-half wr=w; rowl = lane
    const int rowl = lane;
    float m = -3.0e38f, s = 0.f, u = 0.f, m2f = -3.0e38f;
    int idx = 0;
#pragma unroll
    for (int i = 0; i < 4; ++i) {  // ascending wc: deterministic merge order
      const int b = ((w * 4 + i) * 32 + rowl) * 6;
      float m1i = mg[b], si = mg[b + 1], ui = mg[b + 2];
      int ii = __float_as_int(mg[b + 3]);
      float m2i = mg[b + 4];
      s += si; u += ui;
      m2f = fmaxf(m2f, m2i);
      bool up = (m1i > m) || (m1i == m && ii < idx);
      m2f = fmaxf(m2f, up ? m : m1i);  // displaced/losing top-1 feeds top-2
      m = up ? m1i : m;
      idx = up ? ii : idx;
    }
    bool flg = (m - m2f) < DX;  // exact: final top-2 gap below margin

    float ent = logf(s) - u / s;  // = lse - E[logit]
    float tau = 0.5f - 0.2f * (ent * (1.0f / (7.6246190071f + 1e-8f)));
    float simmax = fmaf(m, TEMPR, 1.0f);  // m is (sim-1)/T
    float dist = sqrtf(fmaxf(2.0f - 2.0f * simmax, 0.0f));
    int grow = row0 + w * 32 + rowl;
    float g = CONF[idx] / (1.0f + __expf(-(BS[grow] - tau) * INV_T));
    gate_out[grow] = g;
    gd[grow] = g * dist;
    tau_ws[grow] = tau;
    if (flg) {
      pk[grow] = 0ull;  // init merge slot for krescore4
      int p = atomicAdd(cnt, 1);
      flags[p] = grow;
    }
  }
}

// --- kernel 4: fp32 rescore, chunked (16 chunks/row fan out over blocks) ----
// Chunk = 128 protos. Merge via atomicMax on packed (ordered_sim<<32 | NK-idx):
// exact fp32 compare, smaller idx wins ties, order-independent.
__global__ __launch_bounds__(256) void krescore4(
    const float* __restrict__ E, const float* __restrict__ P,
    const float* __restrict__ invp, const int* __restrict__ cnt,
    const int* __restrict__ flags, u64* __restrict__ pk) {
  const int n = *cnt;
  const int total = n * 16;
  const int t = threadIdx.x;
  const int k = t & 15;   // lane in 16-lane group
  const int G = t >> 4;   // group 0..15

  for (int ch = blockIdx.x; ch < total; ch += gridDim.x) {
    const int j = ch >> 4, q = ch & 15;
    const int row = flags[j];
    // E chunk in registers; 16-lane-group shfl norm (same order as round 7)
    float4 e[8];
    float ss = 0.f;
    const float4* er = (const float4*)(E + (size_t)row * ND);
#pragma unroll
    for (int i = 0; i < 8; ++i) {
      e[i] = er[k + 16 * i];
      ss += e[i].x * e[i].x + e[i].y * e[i].y + e[i].z * e[i].z + e[i].w * e[i].w;
    }
#pragma unroll
    for (int o = 1; o < 16; o <<= 1) ss += __shfl_xor(ss, o);
    const float inv = 1.0f / fmaxf(sqrtf(ss), 1e-12f);
#pragma unroll
    for (int i = 0; i < 8; ++i) {
      e[i].x *= inv; e[i].y *= inv; e[i].z *= inv; e[i].w *= inv;
    }

    float best = -3.0e38f;
    int bidx = NK;
#pragma unroll 2
    for (int m = 0; m < 8; ++m) {  // ascending p within group: first-max kept
      const int p = q * 128 + G + 16 * m;
      const float4* pr = (const float4*)(P + (size_t)p * ND);
      float dot = 0.f;
#pragma unroll
      for (int i = 0; i < 8; ++i) {
        float4 a = pr[k + 16 * i];
        dot = fmaf(a.x, e[i].x, dot); dot = fmaf(a.y, e[i].y, dot);
        dot = fmaf(a.z, e[i].z, dot); dot = fmaf(a.w, e[i].w, dot);
      }
#pragma unroll
      for (int o = 1; o < 16; o <<= 1) dot += __shfl_xor(dot, o);
      float sim = dot * invp[p];
      if (sim > best) { best = sim; bidx = p; }
    }
    if (k == 0) {
      unsigned u = __float_as_uint(best);
      unsigned ord = (u & 0x80000000u) ? ~u : (u | 0x80000000u);
      u64 v = ((u64)ord << 32) | (unsigned)(NK - bidx);
      atomicMax(pk + row, v);
    }
  }
}

// ------- kernel 5: flagged-row fixup (unpack pk) + deterministic mean -------
__global__ __launch_bounds__(1024) void kreduce2(
    float* __restrict__ gd, const float* __restrict__ BS,
    const float* __restrict__ CONF, const float* __restrict__ tau_ws,
    const int* __restrict__ cnt, const int* __restrict__ flags,
    const u64* __restrict__ pk, float* __restrict__ out0,
    float* __restrict__ gate_out) {
  __shared__ float red[1024];
  const int t = threadIdx.x;

  // ---- phase 1: fixup flagged rows from packed rescore results ----
  const int n = *cnt;
  for (int j = t; j < n; j += 1024) {
    const int row = flags[j];
    const u64 v = pk[row];
    const unsigned hi = (unsigned)(v >> 32);
    const int idx = NK - (int)(v & 0xFFFFFFFFu);
    const float sim = (hi & 0x80000000u) ? __uint_as_float(hi & 0x7FFFFFFFu)
                                         : __uint_as_float(~hi);
    const float tau = tau_ws[row];
    const float dist = sqrtf(fmaxf(2.0f - 2.0f * sim, 0.0f));
    const float g = CONF[idx] / (1.0f + __expf(-(BS[row] - tau) * INV_T));
    gate_out[row] = g;
    gd[row] = g * dist;
  }
  __syncthreads();  // block-wide visibility of gd fixups

  // ---- phase 2: deterministic mean ----
  float s = 0.f;
  const float4* g4 = (const float4*)gd;
  for (int i = t; i < 8192; i += 1024) {
    float4 v = g4[i];
    s += (v.x + v.y) + (v.z + v.w);
  }
  red[t] = s;
  __syncthreads();
  for (int off = 512; off > 0; off >>= 1) {
    if (t < off) red[t] += red[t + off];
    __syncthreads();
  }
  if (t == 0) out0[0] = red[0] * (1.0f / 32768.0f);
}

extern "C" void kernel_launch(void* const* d_in, const int* in_sizes, int n_in,
                              void* d_out, int out_size, void* d_ws, size_t ws_size,
                              hipStream_t stream) {
  const float* E = (const float*)d_in[0];
  const float* BS = (const float*)d_in[1];
  const float* P = (const float*)d_in[2];
  const float* CONF = (const float*)d_in[3];
  float* out = (float*)d_out;  // [0]=L_proto, [1..32768]=gate

  char* wsb = (char*)d_ws;
  u16* Phi = (u16*)wsb;                                   // 2 MB @ 0 (transposed)
  u16* Plo = (u16*)(wsb + ((size_t)2 << 20));             // 2 MB @ 2M (transposed)
  u16* Ehi = (u16*)(wsb + ((size_t)4 << 20));             // 32 MB @ 4M (row-major)
  u16* Elo = (u16*)(wsb + ((size_t)36 << 20));            // 32 MB @ 36M
  char* tail = wsb + ((size_t)68 << 20);
  float* tau_ws = (float*)tail;                           // 128 KB
  float* gd = (float*)(tail + 131072);                    // 128 KB
  int* flags = (int*)(tail + 2 * 131072);                 // 128 KB
  int* cnt = (int*)(tail + 3 * 131072);                   // 4 KB pad
  float* invp = (float*)(tail + 3 * 131072 + 4096);       // 8 KB
  u64* pk = (u64*)(tail + 3 * 131072 + 4096 + 8192);      // 256 KB

  kprep_p<<<512, 256, 0, stream>>>(P, Phi, Plo, invp, cnt);
  kprep_e2<<<8192, 256, 0, stream>>>(E, Ehi, Elo);
  kmain_v7<<<512, 512, 0, stream>>>(BS, Phi, Plo, Ehi, Elo, CONF, tau_ws, gd,
                                    out + 1, cnt, flags, pk);
  krescore4<<<2048, 256, 0, stream>>>(E, P, invp, cnt, flags, pk);
  kreduce2<<<1, 1024, 0, stream>>>(gd, BS, CONF, tau_ws, cnt, flags, pk,
                                   out, out + 1);
}

// Round 10
// 959.253 us; speedup vs baseline: 1.5050x; 1.5050x over previous
//
#include <hip/hip_runtime.h>
#include <math.h>

// GatedPrototypeDistillationLoss, MI355X gfx950 — round 10.
// Round-9 failed: 512-thr/(512,4) capped VGPR at 128 < working set (state 80
// + acc + frags) -> spill (VGPR 64, FETCH 1.86GB, MfmaUtil 6%). This kernel's
// softmax state makes <=128-VGPR tiers unreachable; occupancy must come from
// LDS instead:
//  * kmain_v8 = round-8 v6 with BK 32->16: LDS 80->40 KB/block, wave tile
//    32x128 / acc 64 / state 80 / reads:MFMA 10:12 per step ALL unchanged,
//    total LDS+HBM bytes unchanged. __launch_bounds__(256,3) -> 3 blocks/CU
//    (12 waves/CU, was 8). vmcnt(5), 256 steps, digest every 32 steps.
//  * kprep_p re-tiled for BK=16: [kt(8)][dt(32)][g(2)][proto(256)][8].
//  * krescore4 / kreduce2 / epilogue: byte-identical to round 8.

#define NB 32768
#define ND 512
#define NK 2048
#define TEMPR 0.07f
#define INV_T 14.285714285714286f
#define DX 1.4285714e-4f  // near-tie margin in x-domain (=1e-5 sim / T)

typedef unsigned short u16;
typedef unsigned long long u64;
using bf16x8 = __attribute__((ext_vector_type(8))) short;
using u16x8 = __attribute__((ext_vector_type(8))) unsigned short;
using f32x16 = __attribute__((ext_vector_type(16))) float;

__device__ inline u16 bf_hi(float x) {  // fp32 -> bf16 bits, RNE
  unsigned u = __float_as_uint(x);
  u = u + 0x7FFFu + ((u >> 16) & 1u);
  return (u16)(u >> 16);
}
__device__ inline float bf_tof(u16 h) {
  return __uint_as_float(((unsigned)h) << 16);
}
__device__ inline void gload_lds16(const void* g, void* l) {
  __builtin_amdgcn_global_load_lds((const __attribute__((address_space(1))) void*)g,
                                   (__attribute__((address_space(3))) void*)l, 16, 0, 0);
}
#define MF(a, b, c) __builtin_amdgcn_mfma_f32_32x32x16_bf16((a), (b), (c), 0, 0, 0)

#define WAIT_LGKM0 { asm volatile("s_waitcnt lgkmcnt(0)" ::: "memory"); \
                     __builtin_amdgcn_sched_barrier(0); }
#define WAIT_VM5   { asm volatile("s_waitcnt vmcnt(5)" ::: "memory"); \
                     __builtin_amdgcn_sched_barrier(0); }
#define SBAR       { __builtin_amdgcn_s_barrier(); \
                     __builtin_amdgcn_sched_barrier(0); }

// ---- kernel 1: P -> normalized bf16 hi/lo (BK=16 tiles) + inv_p ------------
// Phi/Plo u16 layout: [kt(8)][dt(32)][g(2)][proto(256)][8]
__global__ __launch_bounds__(256) void kprep_p(const float* __restrict__ P,
                                               u16* __restrict__ Phi,
                                               u16* __restrict__ Plo,
                                               float* __restrict__ invp,
                                               int* __restrict__ cnt) {
  if (blockIdx.x == 0 && threadIdx.x == 0) *cnt = 0;
  const int lane = threadIdx.x & 63, w = threadIdx.x >> 6;
  const int p = blockIdx.x * 4 + w;  // grid 512 -> 2048 rows
  const float4* pr = (const float4*)(P + (size_t)p * ND);
  float4 a = pr[2 * lane], b = pr[2 * lane + 1];  // granule `lane`: d=8*lane..+7
  float ss = a.x * a.x + a.y * a.y + a.z * a.z + a.w * a.w
           + b.x * b.x + b.y * b.y + b.z * b.z + b.w * b.w;
#pragma unroll
  for (int off = 32; off > 0; off >>= 1) ss += __shfl_xor(ss, off);
  const float inv = 1.0f / fmaxf(sqrtf(ss), 1e-12f);
  if (lane == 0) invp[p] = inv;
  u16x8 h8, l8;
#define PCNV(j, f) { float n_ = (f) * inv; u16 hb_ = bf_hi(n_); \
  h8[j] = hb_; l8[j] = bf_hi(n_ - bf_tof(hb_)); }
  PCNV(0, a.x) PCNV(1, a.y) PCNV(2, a.z) PCNV(3, a.w)
  PCNV(4, b.x) PCNV(5, b.y) PCNV(6, b.z) PCNV(7, b.w)
#undef PCNV
  const int kt = p >> 8, pl = p & 255;
  // granule lane = dt*2 + g with dt in [0,32), g in {0,1}
  const size_t idx =
      ((size_t)((kt * 32 + (lane >> 1)) * 2 + (lane & 1)) * 256 + pl) * 8;
  *(u16x8*)(Phi + idx) = h8;
  *(u16x8*)(Plo + idx) = l8;
}

// ---------------- kernel 2: E -> normalized bf16 hi/lo (row-major) ----------
__global__ __launch_bounds__(256) void kprep_e2(const float* __restrict__ E,
                                                u16* __restrict__ Ehi,
                                                u16* __restrict__ Elo) {
  const int lane = threadIdx.x & 63, w = threadIdx.x >> 6;
  const int row = blockIdx.x * 4 + w;  // grid 8192 -> 32768 rows
  const float4* er = (const float4*)(E + (size_t)row * ND);
  float4 a = er[lane], b = er[lane + 64];
  float ss = a.x * a.x + a.y * a.y + a.z * a.z + a.w * a.w
           + b.x * b.x + b.y * b.y + b.z * b.z + b.w * b.w;
#pragma unroll
  for (int off = 32; off > 0; off >>= 1) ss += __shfl_xor(ss, off);
  const float inv = 1.0f / fmaxf(sqrtf(ss), 1e-12f);
  ushort4 h4, l4;
#define PCNV(dst_h, dst_l, f) { float n_ = (f) * inv; u16 hb_ = bf_hi(n_); \
  dst_h = hb_; dst_l = bf_hi(n_ - bf_tof(hb_)); }
  PCNV(h4.x, l4.x, a.x) PCNV(h4.y, l4.y, a.y) PCNV(h4.z, l4.z, a.z) PCNV(h4.w, l4.w, a.w)
  *(ushort4*)(Ehi + (size_t)row * ND + lane * 4) = h4;
  *(ushort4*)(Elo + (size_t)row * ND + lane * 4) = l4;
  PCNV(h4.x, l4.x, b.x) PCNV(h4.y, l4.y, b.y) PCNV(h4.z, l4.z, b.z) PCNV(h4.w, l4.w, b.w)
  *(ushort4*)(Ehi + (size_t)row * ND + (lane + 64) * 4) = h4;
  *(ushort4*)(Elo + (size_t)row * ND + (lane + 64) * 4) = l4;
#undef PCNV
}

// online update with exact top-2 tracking (x-domain logit, fixed offset)
#define UPD2(r, vv, pp) { \
  float x_ = fmaf((vv), INV_T, -INV_T); \
  float e_ = __expf(x_); \
  sS[r] += e_; uS[r] = fmaf(x_, e_, uS[r]); \
  bool u1_ = x_ > m1[r]; \
  float lo_ = u1_ ? m1[r] : x_; \
  m2[r] = fmaxf(m2[r], lo_); \
  m1[r] = u1_ ? x_ : m1[r]; \
  ix[r] = u1_ ? (pp) : ix[r]; }

// ====== kernel 3: BK=16 MFMA GEMM, 40KB LDS, 3 blocks/CU, counted vmcnt =====
__global__ __launch_bounds__(256, 3) void kmain_v8(
    const float* __restrict__ BS,
    const u16* __restrict__ PhiG, const u16* __restrict__ PloG,
    const u16* __restrict__ EhiG, const u16* __restrict__ EloG,
    const float* __restrict__ CONF,
    float* __restrict__ tau_ws, float* __restrict__ gd, float* __restrict__ gate_out,
    int* __restrict__ cnt, int* __restrict__ flags, u64* __restrict__ pk) {
  // LDS u16 layouts: A [g(2)][row(64)][8] ; B [g(2)][proto(256)][8]  (40 KB)
  __shared__ u16 Ahi[2][1024], Alo[2][1024];
  __shared__ u16 Bhi[2][4096], Blo[2][4096];

  const int t = threadIdx.x;
  const int lane = t & 63;
  const int w = t >> 6, wr = w >> 1, wc = w & 1;
  const int c = lane & 31, h = lane >> 5;
  const int swz = (blockIdx.x & 7) * 64 + (blockIdx.x >> 3);  // XCD swizzle (512=8*64)
  const int row0 = swz * 64;

  // A staging: waves 0-1 stage Ahi granule w&1, waves 2-3 stage Alo.
  const int ag = w & 1;
  const u16* Asrc = ((w < 2) ? EhiG : EloG) + (size_t)(row0 + lane) * ND + ag * 8;
  const int aslot = (ag * 64 + lane) * 8;

  // B staging: 2 hi + 2 lo instrs per wave; slot index doubles as src offset.
  int boff[2];
#pragma unroll
  for (int i = 0; i < 2; ++i) boff[i] = ((w * 2 + i) * 64 + lane) * 8;

  // fragment-read offsets (u16 units), lane-contiguous 16B -> conflict-free
  const int ao0 = (h * 64 + wr * 32 + c) * 8;
  const int bo0 = (h * 256 + wc * 128 + c) * 8;

  f32x16 acc0, acc1, acc2, acc3;
#pragma unroll
  for (int i = 0; i < 16; ++i) { acc0[i] = 0.f; acc1[i] = 0.f; acc2[i] = 0.f; acc3[i] = 0.f; }
  float sS[16], uS[16], m1[16], m2[16];
  int ix[16];
#pragma unroll
  for (int r = 0; r < 16; ++r) {
    sS[r] = 0.f; uS[r] = 0.f; m1[r] = -3.0e38f; m2[r] = -3.0e38f; ix[r] = 0;
  }

#define SB8(tile_u16, nx) { \
  _Pragma("unroll") \
  for (int i = 0; i < 2; ++i) { \
    gload_lds16(PhiG + (tile_u16) + boff[i], &Bhi[nx][boff[i]]); \
    gload_lds16(PloG + (tile_u16) + boff[i], &Blo[nx][boff[i]]); \
  } }
#define SA8(col, nx) { \
  if (w < 2) { gload_lds16(Asrc + (col), &Ahi[nx][aslot]); } \
  else       { gload_lds16(Asrc + (col), &Alo[nx][aslot]); } }

  // prologue: stage step 0 -> buf0, step 1 -> buf1; wait step0's 5 only
  SB8(0, 0);
  SA8(0, 0);
  SB8(4096, 1);
  SA8(16, 1);
  WAIT_VM5;
  SBAR;

#pragma unroll 2
  for (int step = 0; step < 256; ++step) {
    const int cur = step & 1;
    // ---- phase R: all 10 fragment reads from buf[cur] ----
    const bf16x8 eh = *(const bf16x8*)&Ahi[cur][ao0];
    const bf16x8 el = *(const bf16x8*)&Alo[cur][ao0];
    const bf16x8 bh0 = *(const bf16x8*)&Bhi[cur][bo0];
    const bf16x8 bh1 = *(const bf16x8*)&Bhi[cur][bo0 + 256];
    const bf16x8 bh2 = *(const bf16x8*)&Bhi[cur][bo0 + 512];
    const bf16x8 bh3 = *(const bf16x8*)&Bhi[cur][bo0 + 768];
    const bf16x8 bl0 = *(const bf16x8*)&Blo[cur][bo0];
    const bf16x8 bl1 = *(const bf16x8*)&Blo[cur][bo0 + 256];
    const bf16x8 bl2 = *(const bf16x8*)&Blo[cur][bo0 + 512];
    const bf16x8 bl3 = *(const bf16x8*)&Blo[cur][bo0 + 768];

    // ---- MFMA pass 1 (hi x hi) ----
    acc0 = MF(eh, bh0, acc0); acc1 = MF(eh, bh1, acc1);
    acc2 = MF(eh, bh2, acc2); acc3 = MF(eh, bh3, acc3);

    // ---- barrier 1: all waves done READING buf[cur]; no vmcnt drain ----
    WAIT_LGKM0;
    SBAR;

    // ---- phase S: stage step+2 into buf[cur] (5 loads/wave) ----
    const int ns = (step < 254) ? step + 2 : 255;  // tail dup, never read
    SB8(ns * 4096, cur);
    SA8((ns & 31) * 16, cur);

    // ---- MFMA passes 2,3 (hi x lo, lo x hi) ----
    acc0 = MF(eh, bl0, acc0); acc1 = MF(eh, bl1, acc1);
    acc2 = MF(eh, bl2, acc2); acc3 = MF(eh, bl3, acc3);
    acc0 = MF(el, bh0, acc0); acc1 = MF(el, bh1, acc1);
    acc2 = MF(el, bh2, acc2); acc3 = MF(el, bh3, acc3);

    if ((step & 31) == 31) {  // kt-tile digest (overlaps in-flight stages)
      const int pidb = (step >> 5) * 256 + wc * 128 + c;
#pragma unroll
      for (int r = 0; r < 16; ++r) {
        UPD2(r, acc0[r], pidb)
        UPD2(r, acc1[r], pidb + 32)
        UPD2(r, acc2[r], pidb + 64)
        UPD2(r, acc3[r], pidb + 96)
        acc0[r] = 0.f; acc1[r] = 0.f; acc2[r] = 0.f; acc3[r] = 0.f;
      }
    }

    // ---- barrier 2: retire ONLY step t+1's 5 loads (counted vmcnt) ----
    WAIT_VM5;
    SBAR;
  }

  __syncthreads();  // full drain (tail dup-stages still write Ahi/Bhi)

  // ---- butterfly merge across the 32 proto-partition lanes ----
#pragma unroll
  for (int off = 1; off < 32; off <<= 1) {
#pragma unroll
    for (int r = 0; r < 16; ++r) {
      float m1o = __shfl_xor(m1[r], off);
      float m2o = __shfl_xor(m2[r], off);
      float so = __shfl_xor(sS[r], off);
      float uo = __shfl_xor(uS[r], off);
      int io = __shfl_xor(ix[r], off);
      sS[r] += so; uS[r] += uo;
      bool up = (m1o > m1[r]) || (m1o == m1[r] && io < ix[r]);
      float losr = (m1o > m1[r]) ? m1[r] : m1o;  // min(m1, m1o)
      m2[r] = fmaxf(fmaxf(m2[r], m2o), losr);
      m1[r] = fmaxf(m1[r], m1o);
      ix[r] = up ? io : ix[r];
    }
  }

  // ---- cross-wave (wc) merge via LDS (alias onto Ahi/Alo, compute done) ----
  float* mg = (float*)&Ahi[0][0];  // [wr][wc][32 rows][6] = 768 floats (3 KB)
  if (c == 0) {
#pragma unroll
    for (int r = 0; r < 16; ++r) {
      int rowl = (r & 3) + 8 * (r >> 2) + 4 * h;
      int base = ((wr * 2 + wc) * 32 + rowl) * 6;
      mg[base + 0] = m1[r];
      mg[base + 1] = sS[r];
      mg[base + 2] = uS[r];
      mg[base + 3] = __int_as_float(ix[r]);
      mg[base + 4] = m2[r];
    }
  }
  __syncthreads();

  if ((w & 1) == 0 && lane < 32) {
    const int rowl = lane;
    const int b0 = ((wr * 2 + 0) * 32 + rowl) * 6;
    const int b1 = ((wr * 2 + 1) * 32 + rowl) * 6;
    float m1a = mg[b0], s0 = mg[b0 + 1], u0 = mg[b0 + 2];
    int i0 = __float_as_int(mg[b0 + 3]);
    float m2a = mg[b0 + 4];
    float m1b = mg[b1], s1 = mg[b1 + 1], u1 = mg[b1 + 2];
    int i1 = __float_as_int(mg[b1 + 3]);
    float m2b = mg[b1 + 4];

    bool up = (m1b > m1a) || (m1b == m1a && i1 < i0);
    float m = fmaxf(m1a, m1b);
    float m2f = fmaxf(fmaxf(m2a, m2b), fminf(m1a, m1b));
    int idx = up ? i1 : i0;
    bool flg = (m - m2f) < DX;  // exact: final top-2 gap below margin
    float s = s0 + s1, u = u0 + u1;

    float ent = logf(s) - u / s;  // = lse - E[logit]
    float tau = 0.5f - 0.2f * (ent * (1.0f / (7.6246190071f + 1e-8f)));
    float simmax = fmaf(m, TEMPR, 1.0f);  // m is (sim-1)/T
    float dist = sqrtf(fmaxf(2.0f - 2.0f * simmax, 0.0f));
    int grow = row0 + wr * 32 + rowl;
    float g = CONF[idx] / (1.0f + __expf(-(BS[grow] - tau) * INV_T));
    gate_out[grow] = g;
    gd[grow] = g * dist;
    tau_ws[grow] = tau;
    if (flg) {
      pk[grow] = 0ull;  // init merge slot for krescore4
      int p = atomicAdd(cnt, 1);
      flags[p] = grow;
    }
  }
}

// --- kernel 4: fp32 rescore, chunked (16 chunks/row fan out over blocks) ----
// Chunk = 128 protos. Merge via atomicMax on packed (ordered_sim<<32 | NK-idx):
// exact fp32 compare, smaller idx wins ties, order-independent.
__global__ __launch_bounds__(256) void krescore4(
    const float* __restrict__ E, const float* __restrict__ P,
    const float* __restrict__ invp, const int* __restrict__ cnt,
    const int* __restrict__ flags, u64* __restrict__ pk) {
  const int n = *cnt;
  const int total = n * 16;
  const int t = threadIdx.x;
  const int k = t & 15;   // lane in 16-lane group
  const int G = t >> 4;   // group 0..15

  for (int ch = blockIdx.x; ch < total; ch += gridDim.x) {
    const int j = ch >> 4, q = ch & 15;
    const int row = flags[j];
    // E chunk in registers; 16-lane-group shfl norm (same order as round 7)
    float4 e[8];
    float ss = 0.f;
    const float4* er = (const float4*)(E + (size_t)row * ND);
#pragma unroll
    for (int i = 0; i < 8; ++i) {
      e[i] = er[k + 16 * i];
      ss += e[i].x * e[i].x + e[i].y * e[i].y + e[i].z * e[i].z + e[i].w * e[i].w;
    }
#pragma unroll
    for (int o = 1; o < 16; o <<= 1) ss += __shfl_xor(ss, o);
    const float inv = 1.0f / fmaxf(sqrtf(ss), 1e-12f);
#pragma unroll
    for (int i = 0; i < 8; ++i) {
      e[i].x *= inv; e[i].y *= inv; e[i].z *= inv; e[i].w *= inv;
    }

    float best = -3.0e38f;
    int bidx = NK;
#pragma unroll 2
    for (int m = 0; m < 8; ++m) {  // ascending p within group: first-max kept
      const int p = q * 128 + G + 16 * m;
      const float4* pr = (const float4*)(P + (size_t)p * ND);
      float dot = 0.f;
#pragma unroll
      for (int i = 0; i < 8; ++i) {
        float4 a = pr[k + 16 * i];
        dot = fmaf(a.x, e[i].x, dot); dot = fmaf(a.y, e[i].y, dot);
        dot = fmaf(a.z, e[i].z, dot); dot = fmaf(a.w, e[i].w, dot);
      }
#pragma unroll
      for (int o = 1; o < 16; o <<= 1) dot += __shfl_xor(dot, o);
      float sim = dot * invp[p];
      if (sim > best) { best = sim; bidx = p; }
    }
    if (k == 0) {
      unsigned u = __float_as_uint(best);
      unsigned ord = (u & 0x80000000u) ? ~u : (u | 0x80000000u);
      u64 v = ((u64)ord << 32) | (unsigned)(NK - bidx);
      atomicMax(pk + row, v);
    }
  }
}

// ------- kernel 5: flagged-row fixup (unpack pk) + deterministic mean -------
__global__ __launch_bounds__(1024) void kreduce2(
    float* __restrict__ gd, const float* __restrict__ BS,
    const float* __restrict__ CONF, const float* __restrict__ tau_ws,
    const int* __restrict__ cnt, const int* __restrict__ flags,
    const u64* __restrict__ pk, float* __restrict__ out0,
    float* __restrict__ gate_out) {
  __shared__ float red[1024];
  const int t = threadIdx.x;

  // ---- phase 1: fixup flagged rows from packed rescore results ----
  const int n = *cnt;
  for (int j = t; j < n; j += 1024) {
    const int row = flags[j];
    const u64 v = pk[row];
    const unsigned hi = (unsigned)(v >> 32);
    const int idx = NK - (int)(v & 0xFFFFFFFFu);
    const float sim = (hi & 0x80000000u) ? __uint_as_float(hi & 0x7FFFFFFFu)
                                         : __uint_as_float(~hi);
    const float tau = tau_ws[row];
    const float dist = sqrtf(fmaxf(2.0f - 2.0f * sim, 0.0f));
    const float g = CONF[idx] / (1.0f + __expf(-(BS[row] - tau) * INV_T));
    gate_out[row] = g;
    gd[row] = g * dist;
  }
  __syncthreads();  // block-wide visibility of gd fixups

  // ---- phase 2: deterministic mean ----
  float s = 0.f;
  const float4* g4 = (const float4*)gd;
  for (int i = t; i < 8192; i += 1024) {
    float4 v = g4[i];
    s += (v.x + v.y) + (v.z + v.w);
  }
  red[t] = s;
  __syncthreads();
  for (int off = 512; off > 0; off >>= 1) {
    if (t < off) red[t] += red[t + off];
    __syncthreads();
  }
  if (t == 0) out0[0] = red[0] * (1.0f / 32768.0f);
}

extern "C" void kernel_launch(void* const* d_in, const int* in_sizes, int n_in,
                              void* d_out, int out_size, void* d_ws, size_t ws_size,
                              hipStream_t stream) {
  const float* E = (const float*)d_in[0];
  const float* BS = (const float*)d_in[1];
  const float* P = (const float*)d_in[2];
  const float* CONF = (const float*)d_in[3];
  float* out = (float*)d_out;  // [0]=L_proto, [1..32768]=gate

  char* wsb = (char*)d_ws;
  u16* Phi = (u16*)wsb;                                   // 2 MB @ 0 (BK16 tiles)
  u16* Plo = (u16*)(wsb + ((size_t)2 << 20));             // 2 MB @ 2M (BK16 tiles)
  u16* Ehi = (u16*)(wsb + ((size_t)4 << 20));             // 32 MB @ 4M (row-major)
  u16* Elo = (u16*)(wsb + ((size_t)36 << 20));            // 32 MB @ 36M
  char* tail = wsb + ((size_t)68 << 20);
  float* tau_ws = (float*)tail;                           // 128 KB
  float* gd = (float*)(tail + 131072);                    // 128 KB
  int* flags = (int*)(tail + 2 * 131072);                 // 128 KB
  int* cnt = (int*)(tail + 3 * 131072);                   // 4 KB pad
  float* invp = (float*)(tail + 3 * 131072 + 4096);       // 8 KB
  u64* pk = (u64*)(tail + 3 * 131072 + 4096 + 8192);      // 256 KB

  kprep_p<<<512, 256, 0, stream>>>(P, Phi, Plo, invp, cnt);
  kprep_e2<<<8192, 256, 0, stream>>>(E, Ehi, Elo);
  kmain_v8<<<512, 256, 0, stream>>>(BS, Phi, Plo, Ehi, Elo, CONF, tau_ws, gd,
                                    out + 1, cnt, flags, pk);
  krescore4<<<2048, 256, 0, stream>>>(E, P, invp, cnt, flags, pk);
  kreduce2<<<1, 1024, 0, stream>>>(gd, BS, CONF, tau_ws, cnt, flags, pk,
                                   out, out + 1);
}

// Round 11
// 280.543 us; speedup vs baseline: 5.1461x; 3.4193x over previous
//
#include <hip/hip_runtime.h>
#include <math.h>

// GatedPrototypeDistillationLoss, MI355X gfx950 — round 11.
// Rounds 9/10 proved the 80-reg per-lane softmax state (16 rows x 5) blocks
// any occupancy > 2 waves/SIMD (alloc splits the unified file ~50/50; arch
// half 84 < working set 120 -> scratch spill). Fix: TRANSPOSE the GEMM
// (compute P.E^T): output rows = protos, cols = E-rows -> each lane owns ONE
// E-row; digest folds its 64 proto-slots into 4 substates = 20 regs of state.
//  * kmain_v9: BK16, 40KB LDS, __launch_bounds__(256,3) -> 3 blocks/CU
//    (12 waves/CU). Same 2-phase counted-vmcnt skeleton as rounds 8/10.
//    A(protos, from Phi/Plo BK16 tiles) 32KB dbuf; B(E-rows) 8KB dbuf.
//  * kprep_p (BK16 tiled layout), kprep_e2, krescore4, kreduce2: unchanged.

#define NB 32768
#define ND 512
#define NK 2048
#define TEMPR 0.07f
#define INV_T 14.285714285714286f
#define DX 1.4285714e-4f  // near-tie margin in x-domain (=1e-5 sim / T)

typedef unsigned short u16;
typedef unsigned long long u64;
using bf16x8 = __attribute__((ext_vector_type(8))) short;
using u16x8 = __attribute__((ext_vector_type(8))) unsigned short;
using f32x16 = __attribute__((ext_vector_type(16))) float;

__device__ inline u16 bf_hi(float x) {  // fp32 -> bf16 bits, RNE
  unsigned u = __float_as_uint(x);
  u = u + 0x7FFFu + ((u >> 16) & 1u);
  return (u16)(u >> 16);
}
__device__ inline float bf_tof(u16 h) {
  return __uint_as_float(((unsigned)h) << 16);
}
__device__ inline void gload_lds16(const void* g, void* l) {
  __builtin_amdgcn_global_load_lds((const __attribute__((address_space(1))) void*)g,
                                   (__attribute__((address_space(3))) void*)l, 16, 0, 0);
}
#define MF(a, b, c) __builtin_amdgcn_mfma_f32_32x32x16_bf16((a), (b), (c), 0, 0, 0)

#define WAIT_LGKM0 { asm volatile("s_waitcnt lgkmcnt(0)" ::: "memory"); \
                     __builtin_amdgcn_sched_barrier(0); }
#define WAIT_VM5   { asm volatile("s_waitcnt vmcnt(5)" ::: "memory"); \
                     __builtin_amdgcn_sched_barrier(0); }
#define SBAR       { __builtin_amdgcn_s_barrier(); \
                     __builtin_amdgcn_sched_barrier(0); }

// ---- kernel 1: P -> normalized bf16 hi/lo (BK=16 tiles) + inv_p ------------
// Phi/Plo u16 layout: [kt(8)][dt(32)][g(2)][proto(256)][8]
__global__ __launch_bounds__(256) void kprep_p(const float* __restrict__ P,
                                               u16* __restrict__ Phi,
                                               u16* __restrict__ Plo,
                                               float* __restrict__ invp,
                                               int* __restrict__ cnt) {
  if (blockIdx.x == 0 && threadIdx.x == 0) *cnt = 0;
  const int lane = threadIdx.x & 63, w = threadIdx.x >> 6;
  const int p = blockIdx.x * 4 + w;  // grid 512 -> 2048 rows
  const float4* pr = (const float4*)(P + (size_t)p * ND);
  float4 a = pr[2 * lane], b = pr[2 * lane + 1];  // granule `lane`: d=8*lane..+7
  float ss = a.x * a.x + a.y * a.y + a.z * a.z + a.w * a.w
           + b.x * b.x + b.y * b.y + b.z * b.z + b.w * b.w;
#pragma unroll
  for (int off = 32; off > 0; off >>= 1) ss += __shfl_xor(ss, off);
  const float inv = 1.0f / fmaxf(sqrtf(ss), 1e-12f);
  if (lane == 0) invp[p] = inv;
  u16x8 h8, l8;
#define PCNV(j, f) { float n_ = (f) * inv; u16 hb_ = bf_hi(n_); \
  h8[j] = hb_; l8[j] = bf_hi(n_ - bf_tof(hb_)); }
  PCNV(0, a.x) PCNV(1, a.y) PCNV(2, a.z) PCNV(3, a.w)
  PCNV(4, b.x) PCNV(5, b.y) PCNV(6, b.z) PCNV(7, b.w)
#undef PCNV
  const int kt = p >> 8, pl = p & 255;
  // granule lane = dt*2 + g with dt in [0,32), g in {0,1}
  const size_t idx =
      ((size_t)((kt * 32 + (lane >> 1)) * 2 + (lane & 1)) * 256 + pl) * 8;
  *(u16x8*)(Phi + idx) = h8;
  *(u16x8*)(Plo + idx) = l8;
}

// ---------------- kernel 2: E -> normalized bf16 hi/lo (row-major) ----------
__global__ __launch_bounds__(256) void kprep_e2(const float* __restrict__ E,
                                                u16* __restrict__ Ehi,
                                                u16* __restrict__ Elo) {
  const int lane = threadIdx.x & 63, w = threadIdx.x >> 6;
  const int row = blockIdx.x * 4 + w;  // grid 8192 -> 32768 rows
  const float4* er = (const float4*)(E + (size_t)row * ND);
  float4 a = er[lane], b = er[lane + 64];
  float ss = a.x * a.x + a.y * a.y + a.z * a.z + a.w * a.w
           + b.x * b.x + b.y * b.y + b.z * b.z + b.w * b.w;
#pragma unroll
  for (int off = 32; off > 0; off >>= 1) ss += __shfl_xor(ss, off);
  const float inv = 1.0f / fmaxf(sqrtf(ss), 1e-12f);
  ushort4 h4, l4;
#define PCNV(dst_h, dst_l, f) { float n_ = (f) * inv; u16 hb_ = bf_hi(n_); \
  dst_h = hb_; dst_l = bf_hi(n_ - bf_tof(hb_)); }
  PCNV(h4.x, l4.x, a.x) PCNV(h4.y, l4.y, a.y) PCNV(h4.z, l4.z, a.z) PCNV(h4.w, l4.w, a.w)
  *(ushort4*)(Ehi + (size_t)row * ND + lane * 4) = h4;
  *(ushort4*)(Elo + (size_t)row * ND + lane * 4) = l4;
  PCNV(h4.x, l4.x, b.x) PCNV(h4.y, l4.y, b.y) PCNV(h4.z, l4.z, b.z) PCNV(h4.w, l4.w, b.w)
  *(ushort4*)(Ehi + (size_t)row * ND + (lane + 64) * 4) = h4;
  *(ushort4*)(Elo + (size_t)row * ND + (lane + 64) * 4) = l4;
#undef PCNV
}

// online update with exact top-2 tracking (x-domain logit, fixed offset),
// substate i (per acc tile)
#define UPD2S(i, vv, pp) { \
  float x_ = fmaf((vv), INV_T, -INV_T); \
  float e_ = __expf(x_); \
  sS[i] += e_; uS[i] = fmaf(x_, e_, uS[i]); \
  bool u1_ = x_ > mm1[i]; \
  float lo_ = u1_ ? mm1[i] : x_; \
  mm2[i] = fmaxf(mm2[i], lo_); \
  mm1[i] = u1_ ? x_ : mm1[i]; \
  ixx[i] = u1_ ? (pp) : ixx[i]; }

// ====== kernel 3: TRANSPOSED MFMA GEMM (rows=protos, cols=E-rows) ===========
// BK16, 40KB LDS, 3 blocks/CU, counted-vmcnt 2-phase pipeline.
__global__ __launch_bounds__(256, 3) void kmain_v9(
    const float* __restrict__ BS,
    const u16* __restrict__ PhiG, const u16* __restrict__ PloG,
    const u16* __restrict__ EhiG, const u16* __restrict__ EloG,
    const float* __restrict__ CONF,
    float* __restrict__ tau_ws, float* __restrict__ gd, float* __restrict__ gate_out,
    int* __restrict__ cnt, int* __restrict__ flags, u64* __restrict__ pk) {
  // LDS u16 layouts: A(protos) [g(2)][proto(256)][8] ; B(E-rows) [g(2)][erow(64)][8]
  __shared__ u16 Ahi[2][4096], Alo[2][4096];   // 32 KB
  __shared__ u16 Bhi[2][1024], Blo[2][1024];   // 8 KB

  const int t = threadIdx.x;
  const int lane = t & 63;
  const int w = t >> 6;
  const int wr = w & 1;   // proto half (protos wr*128..+127 of the kt tile)
  const int wc = w >> 1;  // E-row half (erows wc*32..+31)
  const int c = lane & 31, h = lane >> 5;
  const int swz = (blockIdx.x & 7) * 64 + (blockIdx.x >> 3);  // XCD swizzle (512=8*64)
  const int row0 = swz * 64;

  // A staging (protos): 2 hi + 2 lo instrs per wave; slot doubles as src offset
  int aoff[2];
#pragma unroll
  for (int i = 0; i < 2; ++i) aoff[i] = ((w * 2 + i) * 64 + lane) * 8;

  // B staging (E-rows): 1 instr/wave. waves 0-1 -> Bhi (g=w&1), 2-3 -> Blo.
  const u16* Bsrc = ((w < 2) ? EhiG : EloG) + (size_t)(row0 + lane) * ND + (w & 1) * 8;
  const int bslot = ((w & 1) * 64 + lane) * 8;

  // fragment-read offsets (u16 units), lane-contiguous 16B -> conflict-free
  const int arb = (h * 256 + wr * 128 + c) * 8;  // + i*256 for proto tile i
  const int bro = (h * 64 + wc * 32 + c) * 8;

  f32x16 acc0, acc1, acc2, acc3;
#pragma unroll
  for (int i = 0; i < 16; ++i) { acc0[i] = 0.f; acc1[i] = 0.f; acc2[i] = 0.f; acc3[i] = 0.f; }
  // 4 substates (one per proto tile): 20 regs total (was 80 in row-8 layout)
  float sS[4], uS[4], mm1[4], mm2[4];
  int ixx[4];
#pragma unroll
  for (int i = 0; i < 4; ++i) {
    sS[i] = 0.f; uS[i] = 0.f; mm1[i] = -3.0e38f; mm2[i] = -3.0e38f; ixx[i] = 0;
  }

#define SA9(tile_u16, nx) { \
  _Pragma("unroll") \
  for (int i = 0; i < 2; ++i) { \
    gload_lds16(PhiG + (tile_u16) + aoff[i], &Ahi[nx][aoff[i]]); \
    gload_lds16(PloG + (tile_u16) + aoff[i], &Alo[nx][aoff[i]]); \
  } }
#define SB9(col, nx) { \
  if (w < 2) { gload_lds16(Bsrc + (col), &Bhi[nx][bslot]); } \
  else       { gload_lds16(Bsrc + (col), &Blo[nx][bslot]); } }

  // prologue: stage step 0 -> buf0, step 1 -> buf1; wait step0's 5 only
  SA9(0, 0);
  SB9(0, 0);
  SA9(4096, 1);
  SB9(16, 1);
  WAIT_VM5;
  SBAR;

#pragma unroll 2
  for (int step = 0; step < 256; ++step) {
    const int cur = step & 1;
    // ---- phase R: all 10 fragment reads from buf[cur] ----
    const bf16x8 bh = *(const bf16x8*)&Bhi[cur][bro];
    const bf16x8 bl = *(const bf16x8*)&Blo[cur][bro];
    const bf16x8 ah0 = *(const bf16x8*)&Ahi[cur][arb];
    const bf16x8 ah1 = *(const bf16x8*)&Ahi[cur][arb + 256];
    const bf16x8 ah2 = *(const bf16x8*)&Ahi[cur][arb + 512];
    const bf16x8 ah3 = *(const bf16x8*)&Ahi[cur][arb + 768];
    const bf16x8 al0 = *(const bf16x8*)&Alo[cur][arb];
    const bf16x8 al1 = *(const bf16x8*)&Alo[cur][arb + 256];
    const bf16x8 al2 = *(const bf16x8*)&Alo[cur][arb + 512];
    const bf16x8 al3 = *(const bf16x8*)&Alo[cur][arb + 768];

    // ---- MFMA pass 1 (Ahi x Bhi) ----
    acc0 = MF(ah0, bh, acc0); acc1 = MF(ah1, bh, acc1);
    acc2 = MF(ah2, bh, acc2); acc3 = MF(ah3, bh, acc3);

    // ---- barrier 1: all waves done READING buf[cur]; no vmcnt drain ----
    WAIT_LGKM0;
    SBAR;

    // ---- phase S: stage step+2 into buf[cur] (5 loads/wave) ----
    const int ns = (step < 254) ? step + 2 : 255;  // tail dup, never read
    SA9(ns * 4096, cur);
    SB9((ns & 31) * 16, cur);

    // ---- MFMA passes 2,3 (Ahi x Blo, Alo x Bhi) ----
    acc0 = MF(ah0, bl, acc0); acc1 = MF(ah1, bl, acc1);
    acc2 = MF(ah2, bl, acc2); acc3 = MF(ah3, bl, acc3);
    acc0 = MF(al0, bh, acc0); acc1 = MF(al1, bh, acc1);
    acc2 = MF(al2, bh, acc2); acc3 = MF(al3, bh, acc3);

    if ((step & 31) == 31) {  // kt-tile digest (overlaps in-flight stages)
      const int pb = (step >> 5) * 256 + wr * 128 + 4 * h;
#define DIG(i, ACC) { \
  _Pragma("unroll") \
  for (int r = 0; r < 16; ++r) { \
    UPD2S(i, ACC[r], pb + (i)*32 + (r & 3) + 8 * (r >> 2)) \
    ACC[r] = 0.f; \
  } }
      DIG(0, acc0)
      DIG(1, acc1)
      DIG(2, acc2)
      DIG(3, acc3)
#undef DIG
    }

    // ---- barrier 2: retire ONLY step t+1's 5 loads (counted vmcnt) ----
    WAIT_VM5;
    SBAR;
  }

  __syncthreads();  // full drain (tail dup-stages still write Ahi/Bhi)

  // ---- merge 4 substates in-lane (ascending proto tiles; idx tie-break) ----
  float s = 0.f, u = 0.f, m = -3.0e38f, m2f = -3.0e38f;
  int idx = 0;
#pragma unroll
  for (int i = 0; i < 4; ++i) {
    s += sS[i]; u += uS[i];
    bool up = (mm1[i] > m) || (mm1[i] == m && ixx[i] < idx);
    m2f = fmaxf(m2f, mm2[i]);
    m2f = fmaxf(m2f, up ? m : mm1[i]);
    m = up ? mm1[i] : m;
    idx = up ? ixx[i] : idx;
  }

  // ---- h-merge: lanes c and c+32 hold complementary proto halves ----
  {
    float mo = __shfl_xor(m, 32);
    float so = __shfl_xor(s, 32);
    float uo = __shfl_xor(u, 32);
    float m2o = __shfl_xor(m2f, 32);
    int io = __shfl_xor(idx, 32);
    s += so; u += uo;
    bool up = (mo > m) || (mo == m && io < idx);
    m2f = fmaxf(m2f, m2o);
    m2f = fmaxf(m2f, up ? m : mo);
    m = up ? mo : m;
    idx = up ? io : idx;
  }

  // ---- cross-wave (wr) merge via LDS (alias onto Ahi, compute done) ----
  float* mg = (float*)&Ahi[0][0];  // [wc(2)][wr(2)][32 erows][6] = 768 floats
  if (lane < 32) {
    const int base = ((wc * 2 + wr) * 32 + c) * 6;
    mg[base + 0] = m;
    mg[base + 1] = s;
    mg[base + 2] = u;
    mg[base + 3] = __int_as_float(idx);
    mg[base + 4] = m2f;
  }
  __syncthreads();

  if (wr == 0 && lane < 32) {  // waves 0 and 2; erow = wc*32 + lane
    const int b0 = ((wc * 2 + 0) * 32 + lane) * 6;
    const int b1 = ((wc * 2 + 1) * 32 + lane) * 6;
    float m1a = mg[b0], s0 = mg[b0 + 1], u0 = mg[b0 + 2];
    int i0 = __float_as_int(mg[b0 + 3]);
    float m2a = mg[b0 + 4];
    float m1b = mg[b1], s1 = mg[b1 + 1], u1 = mg[b1 + 2];
    int i1 = __float_as_int(mg[b1 + 3]);
    float m2b = mg[b1 + 4];

    bool up = (m1b > m1a) || (m1b == m1a && i1 < i0);
    float mf = fmaxf(m1a, m1b);
    float m2ff = fmaxf(fmaxf(m2a, m2b), fminf(m1a, m1b));
    int idxf = up ? i1 : i0;
    bool flg = (mf - m2ff) < DX;  // exact: final top-2 gap below margin
    float sf = s0 + s1, uf = u0 + u1;

    float ent = logf(sf) - uf / sf;  // = lse - E[logit]
    float tau = 0.5f - 0.2f * (ent * (1.0f / (7.6246190071f + 1e-8f)));
    float simmax = fmaf(mf, TEMPR, 1.0f);  // mf is (sim-1)/T
    float dist = sqrtf(fmaxf(2.0f - 2.0f * simmax, 0.0f));
    int grow = row0 + wc * 32 + lane;
    float g = CONF[idxf] / (1.0f + __expf(-(BS[grow] - tau) * INV_T));
    gate_out[grow] = g;
    gd[grow] = g * dist;
    tau_ws[grow] = tau;
    if (flg) {
      pk[grow] = 0ull;  // init merge slot for krescore4
      int p = atomicAdd(cnt, 1);
      flags[p] = grow;
    }
  }
}

// --- kernel 4: fp32 rescore, chunked (16 chunks/row fan out over blocks) ----
// Chunk = 128 protos. Merge via atomicMax on packed (ordered_sim<<32 | NK-idx):
// exact fp32 compare, smaller idx wins ties, order-independent.
__global__ __launch_bounds__(256) void krescore4(
    const float* __restrict__ E, const float* __restrict__ P,
    const float* __restrict__ invp, const int* __restrict__ cnt,
    const int* __restrict__ flags, u64* __restrict__ pk) {
  const int n = *cnt;
  const int total = n * 16;
  const int t = threadIdx.x;
  const int k = t & 15;   // lane in 16-lane group
  const int G = t >> 4;   // group 0..15

  for (int ch = blockIdx.x; ch < total; ch += gridDim.x) {
    const int j = ch >> 4, q = ch & 15;
    const int row = flags[j];
    // E chunk in registers; 16-lane-group shfl norm (same order as round 7)
    float4 e[8];
    float ss = 0.f;
    const float4* er = (const float4*)(E + (size_t)row * ND);
#pragma unroll
    for (int i = 0; i < 8; ++i) {
      e[i] = er[k + 16 * i];
      ss += e[i].x * e[i].x + e[i].y * e[i].y + e[i].z * e[i].z + e[i].w * e[i].w;
    }
#pragma unroll
    for (int o = 1; o < 16; o <<= 1) ss += __shfl_xor(ss, o);
    const float inv = 1.0f / fmaxf(sqrtf(ss), 1e-12f);
#pragma unroll
    for (int i = 0; i < 8; ++i) {
      e[i].x *= inv; e[i].y *= inv; e[i].z *= inv; e[i].w *= inv;
    }

    float best = -3.0e38f;
    int bidx = NK;
#pragma unroll 2
    for (int m = 0; m < 8; ++m) {  // ascending p within group: first-max kept
      const int p = q * 128 + G + 16 * m;
      const float4* pr = (const float4*)(P + (size_t)p * ND);
      float dot = 0.f;
#pragma unroll
      for (int i = 0; i < 8; ++i) {
        float4 a = pr[k + 16 * i];
        dot = fmaf(a.x, e[i].x, dot); dot = fmaf(a.y, e[i].y, dot);
        dot = fmaf(a.z, e[i].z, dot); dot = fmaf(a.w, e[i].w, dot);
      }
#pragma unroll
      for (int o = 1; o < 16; o <<= 1) dot += __shfl_xor(dot, o);
      float sim = dot * invp[p];
      if (sim > best) { best = sim; bidx = p; }
    }
    if (k == 0) {
      unsigned u = __float_as_uint(best);
      unsigned ord = (u & 0x80000000u) ? ~u : (u | 0x80000000u);
      u64 v = ((u64)ord << 32) | (unsigned)(NK - bidx);
      atomicMax(pk + row, v);
    }
  }
}

// ------- kernel 5: flagged-row fixup (unpack pk) + deterministic mean -------
__global__ __launch_bounds__(1024) void kreduce2(
    float* __restrict__ gd, const float* __restrict__ BS,
    const float* __restrict__ CONF, const float* __restrict__ tau_ws,
    const int* __restrict__ cnt, const int* __restrict__ flags,
    const u64* __restrict__ pk, float* __restrict__ out0,
    float* __restrict__ gate_out) {
  __shared__ float red[1024];
  const int t = threadIdx.x;

  // ---- phase 1: fixup flagged rows from packed rescore results ----
  const int n = *cnt;
  for (int j = t; j < n; j += 1024) {
    const int row = flags[j];
    const u64 v = pk[row];
    const unsigned hi = (unsigned)(v >> 32);
    const int idx = NK - (int)(v & 0xFFFFFFFFu);
    const float sim = (hi & 0x80000000u) ? __uint_as_float(hi & 0x7FFFFFFFu)
                                         : __uint_as_float(~hi);
    const float tau = tau_ws[row];
    const float dist = sqrtf(fmaxf(2.0f - 2.0f * sim, 0.0f));
    const float g = CONF[idx] / (1.0f + __expf(-(BS[row] - tau) * INV_T));
    gate_out[row] = g;
    gd[row] = g * dist;
  }
  __syncthreads();  // block-wide visibility of gd fixups

  // ---- phase 2: deterministic mean ----
  float s = 0.f;
  const float4* g4 = (const float4*)gd;
  for (int i = t; i < 8192; i += 1024) {
    float4 v = g4[i];
    s += (v.x + v.y) + (v.z + v.w);
  }
  red[t] = s;
  __syncthreads();
  for (int off = 512; off > 0; off >>= 1) {
    if (t < off) red[t] += red[t + off];
    __syncthreads();
  }
  if (t == 0) out0[0] = red[0] * (1.0f / 32768.0f);
}

extern "C" void kernel_launch(void* const* d_in, const int* in_sizes, int n_in,
                              void* d_out, int out_size, void* d_ws, size_t ws_size,
                              hipStream_t stream) {
  const float* E = (const float*)d_in[0];
  const float* BS = (const float*)d_in[1];
  const float* P = (const float*)d_in[2];
  const float* CONF = (const float*)d_in[3];
  float* out = (float*)d_out;  // [0]=L_proto, [1..32768]=gate

  char* wsb = (char*)d_ws;
  u16* Phi = (u16*)wsb;                                   // 2 MB @ 0 (BK16 tiles)
  u16* Plo = (u16*)(wsb + ((size_t)2 << 20));             // 2 MB @ 2M (BK16 tiles)
  u16* Ehi = (u16*)(wsb + ((size_t)4 << 20));             // 32 MB @ 4M (row-major)
  u16* Elo = (u16*)(wsb + ((size_t)36 << 20));            // 32 MB @ 36M
  char* tail = wsb + ((size_t)68 << 20);
  float* tau_ws = (float*)tail;                           // 128 KB
  float* gd = (float*)(tail + 131072);                    // 128 KB
  int* flags = (int*)(tail + 2 * 131072);                 // 128 KB
  int* cnt = (int*)(tail + 3 * 131072);                   // 4 KB pad
  float* invp = (float*)(tail + 3 * 131072 + 4096);       // 8 KB
  u64* pk = (u64*)(tail + 3 * 131072 + 4096 + 8192);      // 256 KB

  kprep_p<<<512, 256, 0, stream>>>(P, Phi, Plo, invp, cnt);
  kprep_e2<<<8192, 256, 0, stream>>>(E, Ehi, Elo);
  kmain_v9<<<512, 256, 0, stream>>>(BS, Phi, Plo, Ehi, Elo, CONF, tau_ws, gd,
                                    out + 1, cnt, flags, pk);
  krescore4<<<2048, 256, 0, stream>>>(E, P, invp, cnt, flags, pk);
  kreduce2<<<1, 1024, 0, stream>>>(gd, BS, CONF, tau_ws, cnt, flags, pk,
                                   out, out + 1);
}